// Round 8
// baseline (34.696 us; speedup 1.0000x reference)
//
#include <hip/hip_runtime.h>

namespace {

constexpr int kS = 7;
constexpr int kC = 20;
constexpr int kN = 8;
constexpr int kBS = 16384;
constexpr int kCells = kBS * kS * kS;   // 802816 = 3136 * 256
constexpr int kTile = 256;              // cells per block (= block size)
constexpr int kBlocks = kCells / kTile; // 3136
constexpr int kF = 30;                  // floats per cell (120 B)
constexpr int kParts = kBlocks * 4;     // one partial per wave
constexpr float kLambdaCoord = 5.0f;
constexpr float kLambdaNoobj = 0.5f;
constexpr float kEps = 1e-6f;

typedef const __attribute__((address_space(1))) unsigned int gu32;
typedef __attribute__((address_space(3))) unsigned int lu32;

__global__ __launch_bounds__(256) void yolo_loss_kernel(
    const float* __restrict__ outputs,   // [BS,7,7,30]
    const float* __restrict__ gt_boxes,  // [BS,8,4]
    const int* __restrict__ gt_labels,   // [BS,8]
    float* __restrict__ partials) {      // [kParts], one per wave
  __shared__ float lds[kTile * kF];      // 30 KB transpose buffer

  const int tid = threadIdx.x;
  const int lane = tid & 63;
  const int w = tid >> 6;                // wave id, uniform per wave

  // ---- (1) gt loads issue FIRST (oldest vmem -> compiler waits on them
  //      with the DMA still outstanding) ----
  const int c = blockIdx.x * kTile + tid;
  const int bs = c / (kS * kS);
  float g[kN][4];
  const float4* gb4 =
      reinterpret_cast<const float4*>(gt_boxes + (size_t)bs * kN * 4);
#pragma unroll
  for (int n = 0; n < kN; ++n) {
    float4 v = gb4[n];
    g[n][0] = v.x; g[n][1] = v.y; g[n][2] = v.z; g[n][3] = v.w;
  }
  const int4* lb4 = reinterpret_cast<const int4*>(gt_labels + (size_t)bs * kN);
  const int4 lab0 = lb4[0];
  const int4 lab1 = lb4[1];

  // ---- (2) WAVE-PRIVATE async DMA stage: wave w stages its own 64 cells
  //      (7680 B) as 7 full 1 KB global_load_lds + 1 half (lanes 0-31).
  //      No __syncthreads: each lane later reads only its own wave's slice.
  {
    const char* srcb = reinterpret_cast<const char*>(outputs) +
                       ((size_t)blockIdx.x * kTile + (size_t)w * 64) * 120;
    char* dstb = reinterpret_cast<char*>(lds) + w * 7680;
#pragma unroll
    for (int k = 0; k < 7; ++k) {
      __builtin_amdgcn_global_load_lds((gu32*)(srcb + k * 1024 + lane * 16),
                                       (lu32*)(dstb + k * 1024 + lane * 16),
                                       16, 0, 0);
    }
    if (lane < 32) {
      __builtin_amdgcn_global_load_lds((gu32*)(srcb + 7168 + lane * 16),
                                       (lu32*)(dstb + 7168 + lane * 16),
                                       16, 0, 0);
    }
  }
  // keep the gt-dependent math AFTER the DMA issue (it overlaps DMA flight)
  __builtin_amdgcn_sched_barrier(0);

  // ---- (3) gt-dependent math, overlapped with the DMA ----
  float gx1[kN], gx2[kN], gy1[kN], gy2[kN], ga[kN];
#pragma unroll
  for (int n = 0; n < kN; ++n) {
    gx1[n] = g[n][0] - g[n][2] * 0.5f;
    gx2[n] = g[n][0] + g[n][2] * 0.5f;
    gy1[n] = g[n][1] - g[n][3] * 0.5f;
    gy2[n] = g[n][1] + g[n][3] * 0.5f;
    ga[n]  = g[n][2] * g[n][3];
  }
  // candidate gt sqrts (select AFTER sqrt: value-identical to sqrt-of-selected)
  const float sg0w = __builtin_amdgcn_sqrtf(g[0][2]);
  const float sg0h = __builtin_amdgcn_sqrtf(g[0][3]);
  const float sg1w = __builtin_amdgcn_sqrtf(g[1][2]);
  const float sg1h = __builtin_amdgcn_sqrtf(g[1][3]);

  // ---- (4) wave-local drain of the DMA ----
  asm volatile("s_waitcnt vmcnt(0)" ::: "memory");

  // per-thread cell in LDS; word-stride 30 across lanes -> 2-way bank
  // aliasing only (free on CDNA4)
  const float* x = lds + tid * kF;

  // ---- pairwise IOU (v_rcp_f32: ~1ulp, far below the 5.56 threshold) ----
  float iou[2][kN];
#pragma unroll
  for (int b = 0; b < 2; ++b) {
    const float px = x[b * 5 + 0], py = x[b * 5 + 1];
    const float pw = x[b * 5 + 2], ph = x[b * 5 + 3];
    const float px1 = px - pw * 0.5f, px2 = px + pw * 0.5f;
    const float py1 = py - ph * 0.5f, py2 = py + ph * 0.5f;
    const float parea = pw * ph;
#pragma unroll
    for (int n = 0; n < kN; ++n) {
      const float iw = fmaxf(fminf(px2, gx2[n]) - fmaxf(px1, gx1[n]), 0.0f);
      const float ih = fmaxf(fminf(py2, gy2[n]) - fmaxf(py1, gy1[n]), 0.0f);
      const float inter = iw * ih;
      const float uni = parea + ga[n] - inter;
      iou[b][n] = inter * __builtin_amdgcn_rcpf(uni + kEps);
    }
  }

  // ---- j_star scan (first-max wins, matches jnp.argmax) ----
  float best_iou = -1.0f;
  float i0j = 0.0f, i1j = 0.0f;
#pragma unroll
  for (int n = 0; n < kN; ++n) {
    const float m = fmaxf(iou[0][n], iou[1][n]);
    if (m > best_iou) { best_iou = m; i0j = iou[0][n]; i1j = iou[1][n]; }
  }
  const int bb = (i1j > i0j) ? 1 : 0;   // index 0 wins ties

  // ---- selections (reference quirk: best_b indexes gt_boxes' N axis) ----
  const float gsx = bb ? g[1][0] : g[0][0];
  const float gsy = bb ? g[1][1] : g[0][1];
  const float sgw = bb ? sg1w : sg0w;
  const float sgh = bb ? sg1h : sg0h;
  const float psx = bb ? x[5] : x[0];
  const float psy = bb ? x[6] : x[1];
  const float psw = bb ? x[7] : x[2];
  const float psh = bb ? x[8] : x[3];
  const float psc = bb ? x[9] : x[4];

  // ---- localization + confidence ----
  const float dx = psx - gsx;
  const float dy = psy - gsy;
  const float dw = __builtin_amdgcn_sqrtf(psw) - sgw;
  const float dh = __builtin_amdgcn_sqrtf(psh) - sgh;
  const float loc = kLambdaCoord * (dx * dx + dy * dy + dw * dw + dh * dh);
  const float conf_obj = (psc - best_iou) * (psc - best_iou);

  // ---- log-sum-exp over the 20 classes (inputs in [0,1): no max pass) ----
  float se = 0.0f;
#pragma unroll
  for (int k = 0; k < kC; ++k) se += __expf(x[10 + k]);
  const float lse = __logf(se);

  // ---- CE over the 8 labels (dynamic LDS gather); one fma fold ----
  float s8 = 0.0f;
  s8 += x[10 + lab0.x] + x[10 + lab0.y] + x[10 + lab0.z] + x[10 + lab0.w];
  s8 += x[10 + lab1.x] + x[10 + lab1.y] + x[10 + lab1.z] + x[10 + lab1.w];
  const float ce = lse - 0.125f * s8;   // == -(s8 - 8*lse)/8

  // ---- noobj ----
  const float noobj = kLambdaNoobj * (x[4] * x[4] + x[9] * x[9]);

  float val = (best_iou > 0.0f) ? (loc + conf_obj + ce) : noobj;

  // ---- wave reduction only; one partial per wave (no block barrier) ----
#pragma unroll
  for (int off = 32; off > 0; off >>= 1) val += __shfl_down(val, off, 64);
  if (lane == 0) partials[blockIdx.x * 4 + w] = val;
}

__global__ __launch_bounds__(256) void reduce_kernel(
    const float* __restrict__ partials, float* __restrict__ out) {
  float s = 0.0f;
  for (int i = threadIdx.x; i < kParts; i += 256) s += partials[i];
#pragma unroll
  for (int off = 32; off > 0; off >>= 1) s += __shfl_down(s, off, 64);
  __shared__ float ws[4];
  const int lane = threadIdx.x & 63;
  const int wid = threadIdx.x >> 6;
  if (lane == 0) ws[wid] = s;
  __syncthreads();
  if (threadIdx.x == 0) {
    out[0] = (ws[0] + ws[1] + ws[2] + ws[3]) * (1.0f / kBS);  // exact 2^-14
  }
}

}  // namespace

extern "C" void kernel_launch(void* const* d_in, const int* in_sizes, int n_in,
                              void* d_out, int out_size, void* d_ws, size_t ws_size,
                              hipStream_t stream) {
  const float* outputs = (const float*)d_in[0];
  const float* gt_boxes = (const float*)d_in[1];
  const int* gt_labels = (const int*)d_in[2];
  float* out = (float*)d_out;
  float* partials = (float*)d_ws;   // kParts floats = 49 KB

  yolo_loss_kernel<<<kBlocks, kTile, 0, stream>>>(outputs, gt_boxes, gt_labels, partials);
  reduce_kernel<<<1, 256, 0, stream>>>(partials, out);
}

// Round 9
// 29.225 us; speedup vs baseline: 1.1872x; 1.1872x over previous
//
#include <hip/hip_runtime.h>

namespace {

constexpr int kS = 7;
constexpr int kC = 20;
constexpr int kN = 8;
constexpr int kBS = 16384;
constexpr int kCells = kBS * kS * kS;   // 802816 = 3136 * 256
constexpr int kTile = 256;              // cells per tile (= block size)
constexpr int kTiles = kCells / kTile;  // 3136
constexpr int kBlocks = kTiles / 2;     // 1568: each block does 2 tiles
constexpr int kF = 30;                  // floats per cell (120 B)
constexpr float kLambdaCoord = 5.0f;
constexpr float kLambdaNoobj = 0.5f;
constexpr float kEps = 1e-6f;

typedef const __attribute__((address_space(1))) unsigned int gu32;
typedef __attribute__((address_space(3))) unsigned int lu32;

// Wave-private DMA of one wave's 64 cells (7680 B): 7 full 1 KB loads +
// one half (lanes 0-31). Uniform 8 vmcnt increments per wave.
__device__ __forceinline__ void stage_wave(const char* __restrict__ srcb,
                                           char* dstb, int lane) {
#pragma unroll
  for (int k = 0; k < 7; ++k) {
    __builtin_amdgcn_global_load_lds((gu32*)(srcb + k * 1024 + lane * 16),
                                     (lu32*)(dstb + k * 1024 + lane * 16),
                                     16, 0, 0);
  }
  if (lane < 32) {
    __builtin_amdgcn_global_load_lds((gu32*)(srcb + 7168 + lane * 16),
                                     (lu32*)(dstb + 7168 + lane * 16),
                                     16, 0, 0);
  }
}

struct GtPack {
  float g0x, g0y, g1x, g1y;        // centers of gt boxes 0,1 (selection)
  float sg0w, sg0h, sg1w, sg1h;    // sqrt(w),sqrt(h) of gt boxes 0,1
  float gx1[kN], gx2[kN], gy1[kN], gy2[kN], ga[kN];
  int4 la, lb;
};

__device__ __forceinline__ GtPack make_pack(const float g[kN][4], int4 la,
                                            int4 lb) {
  GtPack P;
  P.g0x = g[0][0]; P.g0y = g[0][1];
  P.g1x = g[1][0]; P.g1y = g[1][1];
  P.sg0w = __builtin_amdgcn_sqrtf(g[0][2]);
  P.sg0h = __builtin_amdgcn_sqrtf(g[0][3]);
  P.sg1w = __builtin_amdgcn_sqrtf(g[1][2]);
  P.sg1h = __builtin_amdgcn_sqrtf(g[1][3]);
#pragma unroll
  for (int n = 0; n < kN; ++n) {
    P.gx1[n] = g[n][0] - g[n][2] * 0.5f;
    P.gx2[n] = g[n][0] + g[n][2] * 0.5f;
    P.gy1[n] = g[n][1] - g[n][3] * 0.5f;
    P.gy2[n] = g[n][1] + g[n][3] * 0.5f;
    P.ga[n]  = g[n][2] * g[n][3];
  }
  P.la = la; P.lb = lb;
  return P;
}

__device__ __forceinline__ float cell_loss(const float* __restrict__ x,
                                           const GtPack& P) {
  // pairwise IOU (v_rcp_f32: ~1ulp, far below the 5.56 output threshold)
  float iou[2][kN];
#pragma unroll
  for (int b = 0; b < 2; ++b) {
    const float px = x[b * 5 + 0], py = x[b * 5 + 1];
    const float pw = x[b * 5 + 2], ph = x[b * 5 + 3];
    const float px1 = px - pw * 0.5f, px2 = px + pw * 0.5f;
    const float py1 = py - ph * 0.5f, py2 = py + ph * 0.5f;
    const float parea = pw * ph;
#pragma unroll
    for (int n = 0; n < kN; ++n) {
      const float iw = fmaxf(fminf(px2, P.gx2[n]) - fmaxf(px1, P.gx1[n]), 0.0f);
      const float ih = fmaxf(fminf(py2, P.gy2[n]) - fmaxf(py1, P.gy1[n]), 0.0f);
      const float inter = iw * ih;
      const float uni = parea + P.ga[n] - inter;
      iou[b][n] = inter * __builtin_amdgcn_rcpf(uni + kEps);
    }
  }

  // j_star scan (first-max wins, matches jnp.argmax)
  float best_iou = -1.0f;
  float i0j = 0.0f, i1j = 0.0f;
#pragma unroll
  for (int n = 0; n < kN; ++n) {
    const float m = fmaxf(iou[0][n], iou[1][n]);
    if (m > best_iou) { best_iou = m; i0j = iou[0][n]; i1j = iou[1][n]; }
  }
  const int bb = (i1j > i0j) ? 1 : 0;   // index 0 wins ties

  // selections (reference quirk: best_b indexes gt_boxes' N axis)
  const float gsx = bb ? P.g1x : P.g0x;
  const float gsy = bb ? P.g1y : P.g0y;
  const float sgw = bb ? P.sg1w : P.sg0w;
  const float sgh = bb ? P.sg1h : P.sg0h;
  const float psx = bb ? x[5] : x[0];
  const float psy = bb ? x[6] : x[1];
  const float psw = bb ? x[7] : x[2];
  const float psh = bb ? x[8] : x[3];
  const float psc = bb ? x[9] : x[4];

  const float dx = psx - gsx;
  const float dy = psy - gsy;
  const float dw = __builtin_amdgcn_sqrtf(psw) - sgw;
  const float dh = __builtin_amdgcn_sqrtf(psh) - sgh;
  const float loc = kLambdaCoord * (dx * dx + dy * dy + dw * dw + dh * dh);
  const float conf_obj = (psc - best_iou) * (psc - best_iou);

  // log-sum-exp over 20 classes (inputs in [0,1): no max pass needed)
  float se = 0.0f;
#pragma unroll
  for (int k = 0; k < kC; ++k) se += __expf(x[10 + k]);
  const float lse = __logf(se);

  // CE over the 8 labels (dynamic LDS gather)
  float s8 = 0.0f;
  s8 += x[10 + P.la.x] + x[10 + P.la.y] + x[10 + P.la.z] + x[10 + P.la.w];
  s8 += x[10 + P.lb.x] + x[10 + P.lb.y] + x[10 + P.lb.z] + x[10 + P.lb.w];
  const float ce = lse - 0.125f * s8;

  const float noobj = kLambdaNoobj * (x[4] * x[4] + x[9] * x[9]);

  return (best_iou > 0.0f) ? (loc + conf_obj + ce) : noobj;
}

__global__ __launch_bounds__(256) void yolo_loss_kernel(
    const float* __restrict__ outputs,   // [BS,7,7,30]
    const float* __restrict__ gt_boxes,  // [BS,8,4]
    const int* __restrict__ gt_labels,   // [BS,8]
    float* __restrict__ partials) {      // [kBlocks]
  __shared__ float lds[2][kTile * kF];   // 2 x 30 KB, tile0 / tile1
  __shared__ float ws[4];

  const int tid = threadIdx.x;
  const int lane = tid & 63;
  const int w = tid >> 6;

  const int t0 = blockIdx.x * 2;        // this block's two tiles
  const int c0 = t0 * kTile + tid;
  const int c1 = c0 + kTile;
  const int bs0 = c0 / (kS * kS);
  const int bs1 = c1 / (kS * kS);

  // ---- gt loads for BOTH tiles first (oldest vmem; L2-resident, cheap) ----
  float g0[kN][4], g1[kN][4];
  {
    const float4* a = reinterpret_cast<const float4*>(gt_boxes + (size_t)bs0 * kN * 4);
    const float4* b = reinterpret_cast<const float4*>(gt_boxes + (size_t)bs1 * kN * 4);
#pragma unroll
    for (int n = 0; n < kN; ++n) {
      float4 v = a[n];
      g0[n][0] = v.x; g0[n][1] = v.y; g0[n][2] = v.z; g0[n][3] = v.w;
    }
#pragma unroll
    for (int n = 0; n < kN; ++n) {
      float4 v = b[n];
      g1[n][0] = v.x; g1[n][1] = v.y; g1[n][2] = v.z; g1[n][3] = v.w;
    }
  }
  const int4* la4 = reinterpret_cast<const int4*>(gt_labels + (size_t)bs0 * kN);
  const int4 l0a = la4[0], l0b = la4[1];
  const int4* lb4 = reinterpret_cast<const int4*>(gt_labels + (size_t)bs1 * kN);
  const int4 l1a = lb4[0], l1b = lb4[1];

  // ---- DMA tile0 then tile1 (wave-private slices; no barriers ever) ----
  {
    const char* base = reinterpret_cast<const char*>(outputs);
    stage_wave(base + (size_t)t0 * 30720 + w * 7680,
               reinterpret_cast<char*>(lds[0]) + w * 7680, lane);
    stage_wave(base + (size_t)(t0 + 1) * 30720 + w * 7680,
               reinterpret_cast<char*>(lds[1]) + w * 7680, lane);
  }

  // ---- gt-derived math overlaps DMA flight ----
  const GtPack P0 = make_pack(g0, l0a, l0b);

  // wait: gt + tile0 DMA complete; tile1's 8 DMA loads stay in flight
  asm volatile("s_waitcnt vmcnt(8)" ::: "memory");

  float val = cell_loss(&lds[0][tid * kF], P0);

  const GtPack P1 = make_pack(g1, l1a, l1b);

  asm volatile("s_waitcnt vmcnt(0)" ::: "memory");

  val += cell_loss(&lds[1][tid * kF], P1);

  // ---- block reduction: wave64 shuffle, then LDS across the 4 waves ----
#pragma unroll
  for (int off = 32; off > 0; off >>= 1) val += __shfl_down(val, off, 64);
  if (lane == 0) ws[w] = val;
  __syncthreads();
  if (tid == 0) {
    partials[blockIdx.x] = ws[0] + ws[1] + ws[2] + ws[3];
  }
}

__global__ __launch_bounds__(256) void reduce_kernel(
    const float* __restrict__ partials, float* __restrict__ out) {
  float s = 0.0f;
  for (int i = threadIdx.x; i < kBlocks; i += 256) s += partials[i];
#pragma unroll
  for (int off = 32; off > 0; off >>= 1) s += __shfl_down(s, off, 64);
  __shared__ float ws[4];
  const int lane = threadIdx.x & 63;
  const int wid = threadIdx.x >> 6;
  if (lane == 0) ws[wid] = s;
  __syncthreads();
  if (threadIdx.x == 0) {
    out[0] = (ws[0] + ws[1] + ws[2] + ws[3]) * (1.0f / kBS);  // exact 2^-14
  }
}

}  // namespace

extern "C" void kernel_launch(void* const* d_in, const int* in_sizes, int n_in,
                              void* d_out, int out_size, void* d_ws, size_t ws_size,
                              hipStream_t stream) {
  const float* outputs = (const float*)d_in[0];
  const float* gt_boxes = (const float*)d_in[1];
  const int* gt_labels = (const int*)d_in[2];
  float* out = (float*)d_out;
  float* partials = (float*)d_ws;   // kBlocks floats = 6.125 KB

  yolo_loss_kernel<<<kBlocks, kTile, 0, stream>>>(outputs, gt_boxes, gt_labels, partials);
  reduce_kernel<<<1, 256, 0, stream>>>(partials, out);
}